// Round 4
// baseline (1020.522 us; speedup 1.0000x reference)
//
#include <hip/hip_runtime.h>
#include <cstdint>

#define NN 16000
#define KK 16
#define FIN 32
#define HH 64
#define NE (NN*KK)

// ---------------------------------------------------------------- prep
// pack[i] = (x, y, sq, 0) with sq = round(x^2) + round(y^2) UNFUSED,
// exactly matching np: c*c elementwise then np.sum — contraction disabled.
__global__ __launch_bounds__(256) void prep_kernel(const float* __restrict__ c,
                                                   float4* __restrict__ pack,
                                                   unsigned* __restrict__ gmm) {
#pragma clang fp contract(off)
  int i = blockIdx.x * 256 + threadIdx.x;
  if (i == 0) { gmm[0] = 0x7F800000u; gmm[1] = 0u; }  // min=+inf bits, max=0 (d>=0)
  if (i < NN) {
    float xv = c[2*i], yv = c[2*i+1];
    float xx = xv * xv;            // round(x^2)   (no fma: contract off)
    float yy = yv * yv;            // round(y^2)
    float sq = xx + yy;            // round(xx+yy)
    pack[i] = make_float4(xv, yv, sq, 0.0f);
  }
}

// ---------------------------------------------------------------- knn
// Bit-exact replication of the f32 reference graph (BLAS K=2 sgemm):
//   dot = fma(y_i, y_j, round(x_i*x_j))
//   d2  = round(round(sq_i + sq_j) - 2*dot)     (2*dot exact)
// Contraction disabled so the muls/adds stay separately rounded.
// Sortable key: sign-flipped f32 bits << 32 | j (smallest-index tie-break).
__global__ __launch_bounds__(256) void knn_kernel(const float4* __restrict__ pack,
                                                  int* __restrict__ nbr) {
#pragma clang fp contract(off)
  const int wv = threadIdx.x >> 6;
  const int lane = threadIdx.x & 63;
  const int i = (blockIdx.x << 2) + wv;
  const float4 pi = pack[i];
  unsigned long long kd[KK];
#pragma unroll
  for (int m = 0; m < KK; ++m) kd[m] = ~0ull;
  for (int j = lane; j < NN; j += 64) {
    float4 pj = pack[j];
    float xprod = pi.x * pj.x;                       // round(x_i*x_j)
    float dot   = __builtin_fmaf(pi.y, pj.y, xprod); // fused, matches BLAS
    float S     = pi.z + pj.z;                       // round(sq_i+sq_j)
    float twod  = dot + dot;                         // exact *2
    float d2    = S - twod;                          // one rounding
    unsigned ub = __float_as_uint(d2);
    ub = (ub & 0x80000000u) ? ~ub : (ub | 0x80000000u);   // total-order map
    unsigned long long key = ((unsigned long long)ub << 32) | (unsigned)j;
    if (j != i && key < kd[KK-1]) {
      // branch-free sorted insert (ascending key)
      unsigned long long ck = key;
#pragma unroll
      for (int m = 0; m < KK; ++m) {
        bool sw = ck < kd[m];
        unsigned long long lo = sw ? ck : kd[m];
        unsigned long long hi = sw ? kd[m] : ck;
        kd[m] = lo; ck = hi;
      }
    }
  }
  // 16-round wave merge: min over lane heads (keys globally unique via j bits)
  int res = 0;
  for (int r = 0; r < KK; ++r) {
    unsigned long long md = kd[0];
#pragma unroll
    for (int off = 32; off > 0; off >>= 1) {
      unsigned long long od = __shfl_xor(md, off, 64);
      md = od < md ? od : md;
    }
    if (kd[0] == md) {                      // unique winner lane pops its head
#pragma unroll
      for (int m = 0; m < KK-1; ++m) kd[m] = kd[m+1];
      kd[KK-1] = ~0ull;
    }
    if (lane == r) res = (int)(md & 0xFFFFFFFFull);
  }
  if (lane < KK) nbr[i*KK + lane] = res;
}

// ---------------------------------------------------------------- edge d + global min/max
__global__ __launch_bounds__(256) void edge_kernel(const float* __restrict__ c,
                                                   const int* __restrict__ nbr,
                                                   float* __restrict__ de,
                                                   unsigned* __restrict__ gmm) {
#pragma clang fp contract(off)
  unsigned bmin = 0x7F800000u, bmax = 0u;
  for (int e = blockIdx.x * 256 + threadIdx.x; e < NE; e += gridDim.x * 256) {
    int i = e >> 4;           // dst (center)
    int s = nbr[e];           // src (neighbor)
    float dx = c[2*i]   - c[2*s];
    float dy = c[2*i+1] - c[2*s+1];
    float xx = dx * dx;
    float yy = dy * dy;
    float d  = __builtin_sqrtf(xx + yy);   // IEEE sqrt (no unsafe-math)
    de[e] = d;
    unsigned b = __float_as_uint(d);       // d >= 0: bit order == float order
    bmin = bmin < b ? bmin : b;
    bmax = bmax > b ? bmax : b;
  }
#pragma unroll
  for (int off = 32; off > 0; off >>= 1) {
    unsigned ob = __shfl_xor(bmin, off, 64);
    bmin = bmin < ob ? bmin : ob;
    unsigned oB = __shfl_xor(bmax, off, 64);
    bmax = bmax > oB ? bmax : oB;
  }
  __shared__ unsigned smin[4], smax[4];
  int lane = threadIdx.x & 63, wv = threadIdx.x >> 6;
  if (lane == 0) { smin[wv] = bmin; smax[wv] = bmax; }
  __syncthreads();
  if (threadIdx.x == 0) {
    unsigned m = smin[0], M = smax[0];
    for (int w = 1; w < 4; ++w) {
      m = m < smin[w] ? m : smin[w];
      M = M > smax[w] ? M : smax[w];
    }
    atomicMin(&gmm[0], m);
    atomicMax(&gmm[1], M);
  }
}

// ---------------------------------------------------------------- ew + deg + dis
__global__ __launch_bounds__(256) void ewdeg_kernel(const unsigned* __restrict__ gmm,
                                                    float* __restrict__ de,   // in: d, out: ew
                                                    float* __restrict__ dis) {
#pragma clang fp contract(off)
  int i = blockIdx.x * 256 + threadIdx.x;
  if (i >= NN) return;
  float mx  = __uint_as_float(gmm[1]);
  float rng = mx - __uint_as_float(gmm[0]);
  float deg = 0.0f;                         // edges first, self-loop last (segment_sum order)
  float4* dp = (float4*)(de + i*KK);
#pragma unroll
  for (int q = 0; q < 4; ++q) {
    float4 v = dp[q];
    float e0 = (mx - v.x) / rng;
    float e1 = (mx - v.y) / rng;
    float e2 = (mx - v.z) / rng;
    float e3 = (mx - v.w) / rng;
    deg = deg + e0; deg = deg + e1;
    deg = deg + e2; deg = deg + e3;
    dp[q] = make_float4(e0, e1, e2, e3);
  }
  deg = deg + 1.0f;                         // self-loop weight 1, added last
  dis[i] = 1.0f / __builtin_sqrtf(deg);     // deg >= 1
}

// ---------------------------------------------------------------- dense xw = a @ W  [N,KIN]x[KIN,64]
template<int KIN>
__global__ __launch_bounds__(256) void gemm_kernel(const float* __restrict__ a,
                                                   const float* __restrict__ w,
                                                   float* __restrict__ o) {
  int gid = blockIdx.x * 256 + threadIdx.x;   // N*64 total
  int i = gid >> 6, f = gid & 63;
  const float4* ar = (const float4*)(a + i * KIN);
  float acc = 0.0f;
#pragma unroll
  for (int q = 0; q < KIN/4; ++q) {
    float4 v = ar[q];
    acc = fmaf(v.x, w[(q*4+0)*HH + f], acc);
    acc = fmaf(v.y, w[(q*4+1)*HH + f], acc);
    acc = fmaf(v.z, w[(q*4+2)*HH + f], acc);
    acc = fmaf(v.w, w[(q*4+3)*HH + f], acc);
  }
  o[gid] = acc;
}

// ---------------------------------------------------------------- aggregate + relu (layer 1/2 body)
__global__ __launch_bounds__(256) void agg_relu_kernel(const float* __restrict__ xw,
                                                       const int* __restrict__ nbr,
                                                       const float* __restrict__ ew,
                                                       const float* __restrict__ dis,
                                                       const float* __restrict__ b,
                                                       float* __restrict__ h) {
  int wv = threadIdx.x >> 6, lane = threadIdx.x & 63;
  int i = (blockIdx.x << 2) + wv;
  float di = dis[i];
  float acc = 0.0f;
#pragma unroll 4
  for (int k = 0; k < KK; ++k) {
    int s = nbr[i*KK + k];
    float coef = (dis[s] * ew[i*KK + k]) * di;   // (dis[s]*w)*dis[t]
    acc = fmaf(coef, xw[s*HH + lane], acc);
  }
  acc = fmaf(di * di, xw[i*HH + lane], acc);     // self loop last
  float v = acc + b[lane];
  h[i*HH + lane] = fmaxf(v, 0.0f);
}

// ---------------------------------------------------------------- aggregate + relu + fc (final)
__global__ __launch_bounds__(256) void agg_fc_kernel(const float* __restrict__ xw,
                                                     const int* __restrict__ nbr,
                                                     const float* __restrict__ ew,
                                                     const float* __restrict__ dis,
                                                     const float* __restrict__ b,
                                                     const float* __restrict__ wfc,
                                                     const float* __restrict__ bfc,
                                                     float* __restrict__ out) {
  int wv = threadIdx.x >> 6, lane = threadIdx.x & 63;
  int i = (blockIdx.x << 2) + wv;
  float di = dis[i];
  float acc = 0.0f;
#pragma unroll 4
  for (int k = 0; k < KK; ++k) {
    int s = nbr[i*KK + k];
    float coef = (dis[s] * ew[i*KK + k]) * di;
    acc = fmaf(coef, xw[s*HH + lane], acc);
  }
  acc = fmaf(di * di, xw[i*HH + lane], acc);
  float v = fmaxf(acc + b[lane], 0.0f);             // h2 feature
  float p = v * wfc[lane];                          // h2 @ Wfc  (F_OUT = 1)
#pragma unroll
  for (int off = 32; off > 0; off >>= 1) p = p + __shfl_xor(p, off, 64);
  if (lane == 0) out[i] = p + bfc[0];
}

// ---------------------------------------------------------------- launch
extern "C" void kernel_launch(void* const* d_in, const int* in_sizes, int n_in,
                              void* d_out, int out_size, void* d_ws, size_t ws_size,
                              hipStream_t stream) {
  (void)in_sizes; (void)n_in; (void)out_size; (void)ws_size;
  const float* x   = (const float*)d_in[0];
  const float* c   = (const float*)d_in[1];
  const float* W1  = (const float*)d_in[2];
  const float* b1  = (const float*)d_in[3];
  const float* W2  = (const float*)d_in[4];
  const float* b2  = (const float*)d_in[5];
  const float* Wfc = (const float*)d_in[6];
  const float* bfc = (const float*)d_in[7];
  float* out = (float*)d_out;

  char* ws = (char*)d_ws;
  size_t off = 0;
  auto alloc = [&](size_t bytes) -> void* {
    void* p = ws + off;
    off += (bytes + 255) & ~size_t(255);
    return p;
  };
  float4*   pack = (float4*)  alloc(NN * sizeof(float4));      // 256 KB
  int*      nbr  = (int*)     alloc(NE * sizeof(int));         // 1 MB
  float*    ew   = (float*)   alloc(NE * sizeof(float));       // 1 MB (d then ew in-place)
  float*    dis  = (float*)   alloc(NN * sizeof(float));       // 64 KB
  unsigned* gmm  = (unsigned*)alloc(2 * sizeof(unsigned));
  float*    xw   = (float*)   alloc(NN * HH * sizeof(float));  // 4 MB (xw1, then xw2)
  float*    h1   = (float*)   alloc(NN * HH * sizeof(float));  // 4 MB

  prep_kernel     <<<(NN + 255) / 256, 256, 0, stream>>>(c, pack, gmm);
  knn_kernel      <<<NN / 4,           256, 0, stream>>>(pack, nbr);
  edge_kernel     <<<250,              256, 0, stream>>>(c, nbr, ew, gmm);
  ewdeg_kernel    <<<(NN + 255) / 256, 256, 0, stream>>>(gmm, ew, dis);
  gemm_kernel<FIN><<<NN * HH / 256,    256, 0, stream>>>(x, W1, xw);
  agg_relu_kernel <<<NN / 4,           256, 0, stream>>>(xw, nbr, ew, dis, b1, h1);
  gemm_kernel<HH> <<<NN * HH / 256,    256, 0, stream>>>(h1, W2, xw);
  agg_fc_kernel   <<<NN / 4,           256, 0, stream>>>(xw, nbr, ew, dis, b2, Wfc, bfc, out);
}

// Round 5
// 224.121 us; speedup vs baseline: 4.5535x; 4.5535x over previous
//
#include <hip/hip_runtime.h>
#include <cstdint>

#define NN 16000
#define KK 16
#define FIN 32
#define HH 64
#define NE (NN*KK)
#define GG 64
#define NCELL (GG*GG)

// ---------------------------------------------------------------- prep
// pack[i] = (x, y, sq, 0) with sq = round(x^2) + round(y^2) UNFUSED (np c*c + sum).
// Also zeroes cell counts and inits global min/max cells.
__global__ __launch_bounds__(256) void prep_kernel(const float* __restrict__ c,
                                                   float4* __restrict__ pack,
                                                   unsigned* __restrict__ cnt,
                                                   unsigned* __restrict__ gmm) {
#pragma clang fp contract(off)
  int i = blockIdx.x * 256 + threadIdx.x;
  if (i == 0) { gmm[0] = 0x7F800000u; gmm[1] = 0u; }  // min=+inf bits, max=0 (d>=0)
  if (i < NCELL) cnt[i] = 0u;
  if (i < NN) {
    float xv = c[2*i], yv = c[2*i+1];
    float xx = xv * xv;            // round(x^2)   (no fma: contract off)
    float yy = yv * yv;            // round(y^2)
    float sq = xx + yy;            // round(xx+yy)
    pack[i] = make_float4(xv, yv, sq, 0.0f);
  }
}

// ---------------------------------------------------------------- bin count
__global__ __launch_bounds__(256) void count_kernel(const float* __restrict__ c,
                                                    unsigned* __restrict__ cnt,
                                                    unsigned* __restrict__ cellid) {
  int i = blockIdx.x * 256 + threadIdx.x;
  if (i >= NN) return;
  float xv = c[2*i], yv = c[2*i+1];
  int cx = (int)(xv * GG); cx = cx > GG-1 ? GG-1 : (cx < 0 ? 0 : cx);
  int cy = (int)(yv * GG); cy = cy > GG-1 ? GG-1 : (cy < 0 ? 0 : cy);
  unsigned cell = (unsigned)(cy * GG + cx);
  cellid[i] = cell;
  atomicAdd(&cnt[cell], 1u);
}

// ---------------------------------------------------------------- prefix scan (single block)
__global__ __launch_bounds__(1024) void scan_kernel(const unsigned* __restrict__ cnt,
                                                    unsigned* __restrict__ cstart,
                                                    unsigned* __restrict__ cursor) {
  __shared__ unsigned s[1024];
  int tid = threadIdx.x;
  unsigned c0 = cnt[tid*4+0], c1 = cnt[tid*4+1], c2 = cnt[tid*4+2], c3 = cnt[tid*4+3];
  s[tid] = c0 + c1 + c2 + c3;
  __syncthreads();
  for (int off = 1; off < 1024; off <<= 1) {     // Hillis-Steele inclusive scan
    unsigned v = (tid >= off) ? s[tid - off] : 0u;
    __syncthreads();
    s[tid] += v;
    __syncthreads();
  }
  unsigned b = (tid == 0) ? 0u : s[tid - 1];     // exclusive base
  cstart[tid*4+0] = b; cursor[tid*4+0] = b; b += c0;
  cstart[tid*4+1] = b; cursor[tid*4+1] = b; b += c1;
  cstart[tid*4+2] = b; cursor[tid*4+2] = b; b += c2;
  cstart[tid*4+3] = b; cursor[tid*4+3] = b; b += c3;
  if (tid == 1023) cstart[NCELL] = b;            // == NN
}

// ---------------------------------------------------------------- scatter into cell order
__global__ __launch_bounds__(256) void scatter_kernel(const float4* __restrict__ pack,
                                                      const unsigned* __restrict__ cellid,
                                                      unsigned* __restrict__ cursor,
                                                      float4* __restrict__ sorted) {
  int i = blockIdx.x * 256 + threadIdx.x;
  if (i >= NN) return;
  unsigned p = atomicAdd(&cursor[cellid[i]], 1u);
  float4 v = pack[i];
  v.w = __uint_as_float((unsigned)i);            // carry original index in bits
  sorted[p] = v;
}

// ---------------------------------------------------------------- knn (binned, expanding ring)
// Thread per sorted node. d2 replicates the passing R4 formula bit-exactly:
//   dot = fma(y_i,y_j, round(x_i*x_j)); d2 = round((sq_i+sq_j) - 2*dot)
// Key = map(d2bits)<<32 | j  (smallest-index tie-break). Selection set is
// enumeration-order independent; stop criterion is geometric with margin
// covering the <=~1e-6 Gram-formula noise, so the result equals brute force.
__global__ __launch_bounds__(256) void knn_kernel(const float4* __restrict__ sorted,
                                                  const unsigned* __restrict__ cstart,
                                                  int* __restrict__ nbr) {
#pragma clang fp contract(off)
  int t = blockIdx.x * 256 + threadIdx.x;
  if (t >= NN) return;
  const float4 me = sorted[t];
  const int myid = (int)__float_as_uint(me.w);
  const float h = 1.0f / GG;                     // exact (2^-6)
  int cx = (int)(me.x * GG); cx = cx > GG-1 ? GG-1 : (cx < 0 ? 0 : cx);
  int cy = (int)(me.y * GG); cy = cy > GG-1 ? GG-1 : (cy < 0 ? 0 : cy);

  unsigned long long kd[KK];
#pragma unroll
  for (int m = 0; m < KK; ++m) kd[m] = ~0ull;

  auto scan_cells = [&](int row, int x0, int x1) {
    if (row < 0 || row >= GG) return;
    x0 = x0 < 0 ? 0 : x0;
    x1 = x1 > GG-1 ? GG-1 : x1;
    if (x0 > x1) return;
    unsigned p  = cstart[row*GG + x0];
    unsigned pe = cstart[row*GG + x1 + 1];
    for (; p < pe; ++p) {
      float4 pj = sorted[p];
      int j = (int)__float_as_uint(pj.w);
      float xprod = me.x * pj.x;                      // round(x_i*x_j)
      float dot   = __builtin_fmaf(me.y, pj.y, xprod);
      float S     = me.z + pj.z;                      // round(sq_i+sq_j)
      float twod  = dot + dot;                        // exact *2
      float d2    = S - twod;                         // one rounding
      unsigned ub = __float_as_uint(d2);
      ub = (ub & 0x80000000u) ? ~ub : (ub | 0x80000000u);   // total-order map
      unsigned long long key = ((unsigned long long)ub << 32) | (unsigned)j;
      if (j != myid && key < kd[KK-1]) {
        unsigned long long ck = key;
#pragma unroll
        for (int m = 0; m < KK; ++m) {
          bool sw = ck < kd[m];
          unsigned long long lo = sw ? ck : kd[m];
          unsigned long long hi = sw ? kd[m] : ck;
          kd[m] = lo; ck = hi;
        }
      }
    }
  };

  int R = 2;
  for (int dy = -R; dy <= R; ++dy) scan_cells(cy + dy, cx - R, cx + R);

  while (true) {
    bool whole = (cx - R <= 0) && (cx + R >= GG-1) && (cy - R <= 0) && (cy + R >= GG-1);
    if (whole) break;                               // everything scanned
    if (kd[KK-1] != ~0ull) {
      // min distance from me to any *populated* exterior point (domain is [0,1)^2)
      float edge = 1e30f;
      if (cx - R > 0)    edge = fminf(edge, me.x - (float)(cx - R) * h);
      if (cx + R < GG-1) edge = fminf(edge, (float)(cx + R + 1) * h - me.x);
      if (cy - R > 0)    edge = fminf(edge, me.y - (float)(cy - R) * h);
      if (cy + R < GG-1) edge = fminf(edge, (float)(cy + R + 1) * h - me.y);
      float lim = edge * edge - 1e-5f;              // margin >> Gram noise (~1e-6)
      if (lim > 0.0f) {
        unsigned lb = __float_as_uint(lim) | 0x80000000u;   // map(lim), lim>0
        if ((unsigned)(kd[KK-1] >> 32) <= lb) break;
      }
    }
    ++R;
    scan_cells(cy - R, cx - R, cx + R);             // new perimeter
    scan_cells(cy + R, cx - R, cx + R);
    for (int dy = -(R-1); dy <= R-1; ++dy) {
      scan_cells(cy + dy, cx - R, cx - R);
      scan_cells(cy + dy, cx + R, cx + R);
    }
  }
#pragma unroll
  for (int m = 0; m < KK; ++m) nbr[myid*KK + m] = (int)(kd[m] & 0xFFFFFFFFull);
}

// ---------------------------------------------------------------- edge d + global min/max
__global__ __launch_bounds__(256) void edge_kernel(const float* __restrict__ c,
                                                   const int* __restrict__ nbr,
                                                   float* __restrict__ de,
                                                   unsigned* __restrict__ gmm) {
#pragma clang fp contract(off)
  unsigned bmin = 0x7F800000u, bmax = 0u;
  for (int e = blockIdx.x * 256 + threadIdx.x; e < NE; e += gridDim.x * 256) {
    int i = e >> 4;           // dst (center)
    int s = nbr[e];           // src (neighbor)
    float dx = c[2*i]   - c[2*s];
    float dy = c[2*i+1] - c[2*s+1];
    float xx = dx * dx;
    float yy = dy * dy;
    float d  = __builtin_sqrtf(xx + yy);
    de[e] = d;
    unsigned b = __float_as_uint(d);       // d >= 0: bit order == float order
    bmin = bmin < b ? bmin : b;
    bmax = bmax > b ? bmax : b;
  }
#pragma unroll
  for (int off = 32; off > 0; off >>= 1) {
    unsigned ob = __shfl_xor(bmin, off, 64);
    bmin = bmin < ob ? bmin : ob;
    unsigned oB = __shfl_xor(bmax, off, 64);
    bmax = bmax > oB ? bmax : oB;
  }
  __shared__ unsigned smin[4], smax[4];
  int lane = threadIdx.x & 63, wv = threadIdx.x >> 6;
  if (lane == 0) { smin[wv] = bmin; smax[wv] = bmax; }
  __syncthreads();
  if (threadIdx.x == 0) {
    unsigned m = smin[0], M = smax[0];
    for (int w = 1; w < 4; ++w) {
      m = m < smin[w] ? m : smin[w];
      M = M > smax[w] ? M : smax[w];
    }
    atomicMin(&gmm[0], m);
    atomicMax(&gmm[1], M);
  }
}

// ---------------------------------------------------------------- ew + deg + dis
__global__ __launch_bounds__(256) void ewdeg_kernel(const unsigned* __restrict__ gmm,
                                                    float* __restrict__ de,   // in: d, out: ew
                                                    float* __restrict__ dis) {
#pragma clang fp contract(off)
  int i = blockIdx.x * 256 + threadIdx.x;
  if (i >= NN) return;
  float mx  = __uint_as_float(gmm[1]);
  float rng = mx - __uint_as_float(gmm[0]);
  float deg = 0.0f;                         // edges first, self-loop last (segment_sum order)
  float4* dp = (float4*)(de + i*KK);
#pragma unroll
  for (int q = 0; q < 4; ++q) {
    float4 v = dp[q];
    float e0 = (mx - v.x) / rng;
    float e1 = (mx - v.y) / rng;
    float e2 = (mx - v.z) / rng;
    float e3 = (mx - v.w) / rng;
    deg = deg + e0; deg = deg + e1;
    deg = deg + e2; deg = deg + e3;
    dp[q] = make_float4(e0, e1, e2, e3);
  }
  deg = deg + 1.0f;                         // self-loop weight 1, added last
  dis[i] = 1.0f / __builtin_sqrtf(deg);     // deg >= 1
}

// ---------------------------------------------------------------- dense xw = a @ W  [N,KIN]x[KIN,64]
template<int KIN>
__global__ __launch_bounds__(256) void gemm_kernel(const float* __restrict__ a,
                                                   const float* __restrict__ w,
                                                   float* __restrict__ o) {
  int gid = blockIdx.x * 256 + threadIdx.x;   // N*64 total
  int i = gid >> 6, f = gid & 63;
  const float4* ar = (const float4*)(a + i * KIN);
  float acc = 0.0f;
#pragma unroll
  for (int q = 0; q < KIN/4; ++q) {
    float4 v = ar[q];
    acc = fmaf(v.x, w[(q*4+0)*HH + f], acc);
    acc = fmaf(v.y, w[(q*4+1)*HH + f], acc);
    acc = fmaf(v.z, w[(q*4+2)*HH + f], acc);
    acc = fmaf(v.w, w[(q*4+3)*HH + f], acc);
  }
  o[gid] = acc;
}

// ---------------------------------------------------------------- aggregate + relu (layer 1 body)
__global__ __launch_bounds__(256) void agg_relu_kernel(const float* __restrict__ xw,
                                                       const int* __restrict__ nbr,
                                                       const float* __restrict__ ew,
                                                       const float* __restrict__ dis,
                                                       const float* __restrict__ b,
                                                       float* __restrict__ h) {
  int wv = threadIdx.x >> 6, lane = threadIdx.x & 63;
  int i = (blockIdx.x << 2) + wv;
  float di = dis[i];
  float acc = 0.0f;
#pragma unroll 4
  for (int k = 0; k < KK; ++k) {
    int s = nbr[i*KK + k];
    float coef = (dis[s] * ew[i*KK + k]) * di;   // (dis[s]*w)*dis[t]
    acc = fmaf(coef, xw[s*HH + lane], acc);
  }
  acc = fmaf(di * di, xw[i*HH + lane], acc);     // self loop last
  float v = acc + b[lane];
  h[i*HH + lane] = fmaxf(v, 0.0f);
}

// ---------------------------------------------------------------- aggregate + relu + fc (final)
__global__ __launch_bounds__(256) void agg_fc_kernel(const float* __restrict__ xw,
                                                     const int* __restrict__ nbr,
                                                     const float* __restrict__ ew,
                                                     const float* __restrict__ dis,
                                                     const float* __restrict__ b,
                                                     const float* __restrict__ wfc,
                                                     const float* __restrict__ bfc,
                                                     float* __restrict__ out) {
  int wv = threadIdx.x >> 6, lane = threadIdx.x & 63;
  int i = (blockIdx.x << 2) + wv;
  float di = dis[i];
  float acc = 0.0f;
#pragma unroll 4
  for (int k = 0; k < KK; ++k) {
    int s = nbr[i*KK + k];
    float coef = (dis[s] * ew[i*KK + k]) * di;
    acc = fmaf(coef, xw[s*HH + lane], acc);
  }
  acc = fmaf(di * di, xw[i*HH + lane], acc);
  float v = fmaxf(acc + b[lane], 0.0f);             // h2 feature
  float p = v * wfc[lane];                          // h2 @ Wfc  (F_OUT = 1)
#pragma unroll
  for (int off = 32; off > 0; off >>= 1) p = p + __shfl_xor(p, off, 64);
  if (lane == 0) out[i] = p + bfc[0];
}

// ---------------------------------------------------------------- launch
extern "C" void kernel_launch(void* const* d_in, const int* in_sizes, int n_in,
                              void* d_out, int out_size, void* d_ws, size_t ws_size,
                              hipStream_t stream) {
  (void)in_sizes; (void)n_in; (void)out_size; (void)ws_size;
  const float* x   = (const float*)d_in[0];
  const float* c   = (const float*)d_in[1];
  const float* W1  = (const float*)d_in[2];
  const float* b1  = (const float*)d_in[3];
  const float* W2  = (const float*)d_in[4];
  const float* b2  = (const float*)d_in[5];
  const float* Wfc = (const float*)d_in[6];
  const float* bfc = (const float*)d_in[7];
  float* out = (float*)d_out;

  char* ws = (char*)d_ws;
  size_t off = 0;
  auto alloc = [&](size_t bytes) -> void* {
    void* p = ws + off;
    off += (bytes + 255) & ~size_t(255);
    return p;
  };
  float4*   pack   = (float4*)  alloc(NN * sizeof(float4));       // 256 KB
  float4*   sorted = (float4*)  alloc(NN * sizeof(float4));       // 256 KB
  unsigned* cnt    = (unsigned*)alloc(NCELL * sizeof(unsigned));  // 16 KB
  unsigned* cstart = (unsigned*)alloc((NCELL+1) * sizeof(unsigned));
  unsigned* cursor = (unsigned*)alloc(NCELL * sizeof(unsigned));
  unsigned* cellid = (unsigned*)alloc(NN * sizeof(unsigned));     // 64 KB
  int*      nbr    = (int*)     alloc(NE * sizeof(int));          // 1 MB
  float*    ew     = (float*)   alloc(NE * sizeof(float));        // 1 MB (d then ew in-place)
  float*    dis    = (float*)   alloc(NN * sizeof(float));        // 64 KB
  unsigned* gmm    = (unsigned*)alloc(2 * sizeof(unsigned));
  float*    xw     = (float*)   alloc(NN * HH * sizeof(float));   // 4 MB (xw1, then xw2)
  float*    h1     = (float*)   alloc(NN * HH * sizeof(float));   // 4 MB

  const int NB = (NN + 255) / 256;
  prep_kernel     <<<NB,  256, 0, stream>>>(c, pack, cnt, gmm);
  count_kernel    <<<NB,  256, 0, stream>>>(c, cnt, cellid);
  scan_kernel     <<<1,  1024, 0, stream>>>(cnt, cstart, cursor);
  scatter_kernel  <<<NB,  256, 0, stream>>>(pack, cellid, cursor, sorted);
  knn_kernel      <<<NB,  256, 0, stream>>>(sorted, cstart, nbr);
  edge_kernel     <<<250, 256, 0, stream>>>(c, nbr, ew, gmm);
  ewdeg_kernel    <<<NB,  256, 0, stream>>>(gmm, ew, dis);
  gemm_kernel<FIN><<<NN * HH / 256, 256, 0, stream>>>(x, W1, xw);
  agg_relu_kernel <<<NN / 4,        256, 0, stream>>>(xw, nbr, ew, dis, b1, h1);
  gemm_kernel<HH> <<<NN * HH / 256, 256, 0, stream>>>(h1, W2, xw);
  agg_fc_kernel   <<<NN / 4,        256, 0, stream>>>(xw, nbr, ew, dis, b2, Wfc, bfc, out);
}

// Round 6
// 175.986 us; speedup vs baseline: 5.7989x; 1.2735x over previous
//
#include <hip/hip_runtime.h>
#include <cstdint>

#define NN 16000
#define KK 16
#define FIN 32
#define HH 64
#define NE (NN*KK)
#define GG 64
#define NCELL (GG*GG)

// ---------------------------------------------------------------- prep
// pack[i] = (x, y, sq, 0) with sq = round(x^2) + round(y^2) UNFUSED (np c*c + sum).
// Also zeroes cell counts and inits global min/max cells.
__global__ __launch_bounds__(256) void prep_kernel(const float* __restrict__ c,
                                                   float4* __restrict__ pack,
                                                   unsigned* __restrict__ cnt,
                                                   unsigned* __restrict__ gmm) {
#pragma clang fp contract(off)
  int i = blockIdx.x * 256 + threadIdx.x;
  if (i == 0) { gmm[0] = 0x7F800000u; gmm[1] = 0u; }  // min=+inf bits, max=0 (d>=0)
  if (i < NCELL) cnt[i] = 0u;
  if (i < NN) {
    float xv = c[2*i], yv = c[2*i+1];
    float xx = xv * xv;            // round(x^2)   (no fma: contract off)
    float yy = yv * yv;            // round(y^2)
    float sq = xx + yy;            // round(xx+yy)
    pack[i] = make_float4(xv, yv, sq, 0.0f);
  }
}

// ---------------------------------------------------------------- bin count
__global__ __launch_bounds__(256) void count_kernel(const float* __restrict__ c,
                                                    unsigned* __restrict__ cnt,
                                                    unsigned* __restrict__ cellid) {
  int i = blockIdx.x * 256 + threadIdx.x;
  if (i >= NN) return;
  float xv = c[2*i], yv = c[2*i+1];
  int cx = (int)(xv * GG); cx = cx > GG-1 ? GG-1 : (cx < 0 ? 0 : cx);
  int cy = (int)(yv * GG); cy = cy > GG-1 ? GG-1 : (cy < 0 ? 0 : cy);
  unsigned cell = (unsigned)(cy * GG + cx);
  cellid[i] = cell;
  atomicAdd(&cnt[cell], 1u);
}

// ---------------------------------------------------------------- prefix scan (single block)
__global__ __launch_bounds__(1024) void scan_kernel(const unsigned* __restrict__ cnt,
                                                    unsigned* __restrict__ cstart,
                                                    unsigned* __restrict__ cursor) {
  __shared__ unsigned s[1024];
  int tid = threadIdx.x;
  unsigned c0 = cnt[tid*4+0], c1 = cnt[tid*4+1], c2 = cnt[tid*4+2], c3 = cnt[tid*4+3];
  s[tid] = c0 + c1 + c2 + c3;
  __syncthreads();
  for (int off = 1; off < 1024; off <<= 1) {     // Hillis-Steele inclusive scan
    unsigned v = (tid >= off) ? s[tid - off] : 0u;
    __syncthreads();
    s[tid] += v;
    __syncthreads();
  }
  unsigned b = (tid == 0) ? 0u : s[tid - 1];     // exclusive base
  cstart[tid*4+0] = b; cursor[tid*4+0] = b; b += c0;
  cstart[tid*4+1] = b; cursor[tid*4+1] = b; b += c1;
  cstart[tid*4+2] = b; cursor[tid*4+2] = b; b += c2;
  cstart[tid*4+3] = b; cursor[tid*4+3] = b; b += c3;
  if (tid == 1023) cstart[NCELL] = b;            // == NN
}

// ---------------------------------------------------------------- scatter into cell order
__global__ __launch_bounds__(256) void scatter_kernel(const float4* __restrict__ pack,
                                                      const unsigned* __restrict__ cellid,
                                                      unsigned* __restrict__ cursor,
                                                      float4* __restrict__ sorted,
                                                      int* __restrict__ sid) {
  int i = blockIdx.x * 256 + threadIdx.x;
  if (i >= NN) return;
  unsigned p = atomicAdd(&cursor[cellid[i]], 1u);
  float4 v = pack[i];
  v.w = __uint_as_float((unsigned)i);            // carry original index in bits
  sorted[p] = v;
  sid[p] = i;
}

// ---------------------------------------------------------------- knn (binned, 4 lanes/node)
// Quad of adjacent lanes per node; lane q scans candidates p+q, p+q+4, ...
// d2 formula identical to the passing R4/R5 kernel (bit-exact graph):
//   dot = fma(y_i,y_j, round(x_i*x_j)); d2 = round((sq_i+sq_j) - 2*dot)
// Stop bound: union_16th <= max over quad of per-lane kd[3] (4x4=16 elements
// are all <= that max). Final: 16-round quad-head min-extract merge.
__global__ __launch_bounds__(256) void knn_kernel(const float4* __restrict__ sorted,
                                                  const unsigned* __restrict__ cstart,
                                                  int* __restrict__ nbr) {
#pragma clang fp contract(off)
  int g = blockIdx.x * 256 + threadIdx.x;
  int t = g >> 2;                                // sorted node index
  int q = g & 3;                                 // quad lane
  if (t >= NN) return;
  const float4 me = sorted[t];
  const int myid = (int)__float_as_uint(me.w);
  const float h = 1.0f / GG;                     // exact (2^-6)
  int cx = (int)(me.x * GG); cx = cx > GG-1 ? GG-1 : (cx < 0 ? 0 : cx);
  int cy = (int)(me.y * GG); cy = cy > GG-1 ? GG-1 : (cy < 0 ? 0 : cy);

  unsigned long long kd[KK];
#pragma unroll
  for (int m = 0; m < KK; ++m) kd[m] = ~0ull;

  auto scan_cells = [&](int row, int x0, int x1) {
    if (row < 0 || row >= GG) return;
    x0 = x0 < 0 ? 0 : x0;
    x1 = x1 > GG-1 ? GG-1 : x1;
    if (x0 > x1) return;
    unsigned p  = cstart[row*GG + x0];
    unsigned pe = cstart[row*GG + x1 + 1];
    for (unsigned pp = p + (unsigned)q; pp < pe; pp += 4) {
      float4 pj = sorted[pp];
      int j = (int)__float_as_uint(pj.w);
      float xprod = me.x * pj.x;                      // round(x_i*x_j)
      float dot   = __builtin_fmaf(me.y, pj.y, xprod);
      float S     = me.z + pj.z;                      // round(sq_i+sq_j)
      float twod  = dot + dot;                        // exact *2
      float d2    = S - twod;                         // one rounding
      unsigned ub = __float_as_uint(d2);
      ub = (ub & 0x80000000u) ? ~ub : (ub | 0x80000000u);   // total-order map
      unsigned long long key = ((unsigned long long)ub << 32) | (unsigned)j;
      if (j != myid && key < kd[KK-1]) {
        unsigned long long ck = key;
#pragma unroll
        for (int m = 0; m < KK; ++m) {
          bool sw = ck < kd[m];
          unsigned long long lo = sw ? ck : kd[m];
          unsigned long long hi = sw ? kd[m] : ck;
          kd[m] = lo; ck = hi;
        }
      }
    }
  };

  int R = 2;
  for (int dy = -R; dy <= R; ++dy) scan_cells(cy + dy, cx - R, cx + R);

  while (true) {
    bool whole = (cx - R <= 0) && (cx + R >= GG-1) && (cy - R <= 0) && (cy + R >= GG-1);
    if (whole) break;                               // everything scanned
    // union's 16th smallest <= max over quad of per-lane kd[3]
    unsigned long long b16 = kd[3];
    unsigned long long o1 = __shfl_xor(b16, 1, 64); b16 = o1 > b16 ? o1 : b16;
    unsigned long long o2 = __shfl_xor(b16, 2, 64); b16 = o2 > b16 ? o2 : b16;
    if (b16 != ~0ull) {
      float edge = 1e30f;
      if (cx - R > 0)    edge = fminf(edge, me.x - (float)(cx - R) * h);
      if (cx + R < GG-1) edge = fminf(edge, (float)(cx + R + 1) * h - me.x);
      if (cy - R > 0)    edge = fminf(edge, me.y - (float)(cy - R) * h);
      if (cy + R < GG-1) edge = fminf(edge, (float)(cy + R + 1) * h - me.y);
      float lim = edge * edge - 1e-5f;              // margin >> Gram noise (~1e-6)
      if (lim > 0.0f) {
        unsigned lb = __float_as_uint(lim) | 0x80000000u;   // map(lim), lim>0
        if ((unsigned)(b16 >> 32) <= lb) break;
      }
    }
    ++R;
    scan_cells(cy - R, cx - R, cx + R);             // new perimeter
    scan_cells(cy + R, cx - R, cx + R);
    for (int dy = -(R-1); dy <= R-1; ++dy) {
      scan_cells(cy + dy, cx - R, cx - R);
      scan_cells(cy + dy, cx + R, cx + R);
    }
  }

  // merge 4 sorted per-lane lists -> global top-16 (keys unique via j bits)
  unsigned res[4];
  for (int r = 0; r < KK; ++r) {
    unsigned long long md = kd[0];
    unsigned long long o1 = __shfl_xor(md, 1, 64); md = o1 < md ? o1 : md;
    unsigned long long o2 = __shfl_xor(md, 2, 64); md = o2 < md ? o2 : md;
    if (kd[0] == md) {                              // unique winner lane pops
#pragma unroll
      for (int m = 0; m < KK-1; ++m) kd[m] = kd[m+1];
      kd[KK-1] = ~0ull;
    }
    if ((r >> 2) == q) res[r & 3] = (unsigned)(md & 0xFFFFFFFFull);
  }
  int4 w4;
  w4.x = (int)res[0]; w4.y = (int)res[1]; w4.z = (int)res[2]; w4.w = (int)res[3];
  *(int4*)(nbr + myid*KK + 4*q) = w4;               // 16B aligned (64B row)
}

// ---------------------------------------------------------------- edge d + global min/max
__global__ __launch_bounds__(256) void edge_kernel(const float* __restrict__ c,
                                                   const int* __restrict__ nbr,
                                                   float* __restrict__ de,
                                                   unsigned* __restrict__ gmm) {
#pragma clang fp contract(off)
  unsigned bmin = 0x7F800000u, bmax = 0u;
  for (int e = blockIdx.x * 256 + threadIdx.x; e < NE; e += gridDim.x * 256) {
    int i = e >> 4;           // dst (center)
    int s = nbr[e];           // src (neighbor)
    float dx = c[2*i]   - c[2*s];
    float dy = c[2*i+1] - c[2*s+1];
    float xx = dx * dx;
    float yy = dy * dy;
    float d  = __builtin_sqrtf(xx + yy);
    de[e] = d;
    unsigned b = __float_as_uint(d);       // d >= 0: bit order == float order
    bmin = bmin < b ? bmin : b;
    bmax = bmax > b ? bmax : b;
  }
#pragma unroll
  for (int off = 32; off > 0; off >>= 1) {
    unsigned ob = __shfl_xor(bmin, off, 64);
    bmin = bmin < ob ? bmin : ob;
    unsigned oB = __shfl_xor(bmax, off, 64);
    bmax = bmax > oB ? bmax : oB;
  }
  __shared__ unsigned smin[4], smax[4];
  int lane = threadIdx.x & 63, wv = threadIdx.x >> 6;
  if (lane == 0) { smin[wv] = bmin; smax[wv] = bmax; }
  __syncthreads();
  if (threadIdx.x == 0) {
    unsigned m = smin[0], M = smax[0];
    for (int w = 1; w < 4; ++w) {
      m = m < smin[w] ? m : smin[w];
      M = M > smax[w] ? M : smax[w];
    }
    atomicMin(&gmm[0], m);
    atomicMax(&gmm[1], M);
  }
}

// ---------------------------------------------------------------- ew + deg + dis
__global__ __launch_bounds__(256) void ewdeg_kernel(const unsigned* __restrict__ gmm,
                                                    float* __restrict__ de,   // in: d, out: ew
                                                    float* __restrict__ dis) {
#pragma clang fp contract(off)
  int i = blockIdx.x * 256 + threadIdx.x;
  if (i >= NN) return;
  float mx  = __uint_as_float(gmm[1]);
  float rng = mx - __uint_as_float(gmm[0]);
  float deg = 0.0f;                         // edges first, self-loop last (segment_sum order)
  float4* dp = (float4*)(de + i*KK);
#pragma unroll
  for (int q = 0; q < 4; ++q) {
    float4 v = dp[q];
    float e0 = (mx - v.x) / rng;
    float e1 = (mx - v.y) / rng;
    float e2 = (mx - v.z) / rng;
    float e3 = (mx - v.w) / rng;
    deg = deg + e0; deg = deg + e1;
    deg = deg + e2; deg = deg + e3;
    dp[q] = make_float4(e0, e1, e2, e3);
  }
  deg = deg + 1.0f;                         // self-loop weight 1, added last
  dis[i] = 1.0f / __builtin_sqrtf(deg);     // deg >= 1
}

// ---------------------------------------------------------------- dense xw = a @ W  [N,KIN]x[KIN,64]
template<int KIN>
__global__ __launch_bounds__(256) void gemm_kernel(const float* __restrict__ a,
                                                   const float* __restrict__ w,
                                                   float* __restrict__ o) {
  int gid = blockIdx.x * 256 + threadIdx.x;   // N*64 total
  int i = gid >> 6, f = gid & 63;
  const float4* ar = (const float4*)(a + i * KIN);
  float acc = 0.0f;
#pragma unroll
  for (int q = 0; q < KIN/4; ++q) {
    float4 v = ar[q];
    acc = fmaf(v.x, w[(q*4+0)*HH + f], acc);
    acc = fmaf(v.y, w[(q*4+1)*HH + f], acc);
    acc = fmaf(v.z, w[(q*4+2)*HH + f], acc);
    acc = fmaf(v.w, w[(q*4+3)*HH + f], acc);
  }
  o[gid] = acc;
}

// ---------------------------------------------------------------- aggregate + relu (layer 1 body)
// Iterates in spatially-sorted order (sid) for gather locality; per-node
// arithmetic identical to before -> bit-identical output.
__global__ __launch_bounds__(256) void agg_relu_kernel(const float* __restrict__ xw,
                                                       const int* __restrict__ nbr,
                                                       const float* __restrict__ ew,
                                                       const float* __restrict__ dis,
                                                       const float* __restrict__ b,
                                                       const int* __restrict__ sid,
                                                       float* __restrict__ h) {
  int wv = threadIdx.x >> 6, lane = threadIdx.x & 63;
  int i = sid[(blockIdx.x << 2) + wv];
  float di = dis[i];
  float acc = 0.0f;
#pragma unroll 4
  for (int k = 0; k < KK; ++k) {
    int s = nbr[i*KK + k];
    float coef = (dis[s] * ew[i*KK + k]) * di;   // (dis[s]*w)*dis[t]
    acc = fmaf(coef, xw[s*HH + lane], acc);
  }
  acc = fmaf(di * di, xw[i*HH + lane], acc);     // self loop last
  float v = acc + b[lane];
  h[i*HH + lane] = fmaxf(v, 0.0f);
}

// ---------------------------------------------------------------- aggregate + relu + fc (final)
__global__ __launch_bounds__(256) void agg_fc_kernel(const float* __restrict__ xw,
                                                     const int* __restrict__ nbr,
                                                     const float* __restrict__ ew,
                                                     const float* __restrict__ dis,
                                                     const float* __restrict__ b,
                                                     const float* __restrict__ wfc,
                                                     const float* __restrict__ bfc,
                                                     const int* __restrict__ sid,
                                                     float* __restrict__ out) {
  int wv = threadIdx.x >> 6, lane = threadIdx.x & 63;
  int i = sid[(blockIdx.x << 2) + wv];
  float di = dis[i];
  float acc = 0.0f;
#pragma unroll 4
  for (int k = 0; k < KK; ++k) {
    int s = nbr[i*KK + k];
    float coef = (dis[s] * ew[i*KK + k]) * di;
    acc = fmaf(coef, xw[s*HH + lane], acc);
  }
  acc = fmaf(di * di, xw[i*HH + lane], acc);
  float v = fmaxf(acc + b[lane], 0.0f);             // h2 feature
  float p = v * wfc[lane];                          // h2 @ Wfc  (F_OUT = 1)
#pragma unroll
  for (int off = 32; off > 0; off >>= 1) p = p + __shfl_xor(p, off, 64);
  if (lane == 0) out[i] = p + bfc[0];
}

// ---------------------------------------------------------------- launch
extern "C" void kernel_launch(void* const* d_in, const int* in_sizes, int n_in,
                              void* d_out, int out_size, void* d_ws, size_t ws_size,
                              hipStream_t stream) {
  (void)in_sizes; (void)n_in; (void)out_size; (void)ws_size;
  const float* x   = (const float*)d_in[0];
  const float* c   = (const float*)d_in[1];
  const float* W1  = (const float*)d_in[2];
  const float* b1  = (const float*)d_in[3];
  const float* W2  = (const float*)d_in[4];
  const float* b2  = (const float*)d_in[5];
  const float* Wfc = (const float*)d_in[6];
  const float* bfc = (const float*)d_in[7];
  float* out = (float*)d_out;

  char* ws = (char*)d_ws;
  size_t off = 0;
  auto alloc = [&](size_t bytes) -> void* {
    void* p = ws + off;
    off += (bytes + 255) & ~size_t(255);
    return p;
  };
  float4*   pack   = (float4*)  alloc(NN * sizeof(float4));       // 256 KB
  float4*   sorted = (float4*)  alloc(NN * sizeof(float4));       // 256 KB
  unsigned* cnt    = (unsigned*)alloc(NCELL * sizeof(unsigned));  // 16 KB
  unsigned* cstart = (unsigned*)alloc((NCELL+1) * sizeof(unsigned));
  unsigned* cursor = (unsigned*)alloc(NCELL * sizeof(unsigned));
  unsigned* cellid = (unsigned*)alloc(NN * sizeof(unsigned));     // 64 KB
  int*      sid    = (int*)     alloc(NN * sizeof(int));          // 64 KB
  int*      nbr    = (int*)     alloc(NE * sizeof(int));          // 1 MB
  float*    ew     = (float*)   alloc(NE * sizeof(float));        // 1 MB (d then ew in-place)
  float*    dis    = (float*)   alloc(NN * sizeof(float));        // 64 KB
  unsigned* gmm    = (unsigned*)alloc(2 * sizeof(unsigned));
  float*    xw     = (float*)   alloc(NN * HH * sizeof(float));   // 4 MB (xw1, then xw2)
  float*    h1     = (float*)   alloc(NN * HH * sizeof(float));   // 4 MB

  const int NB = (NN + 255) / 256;
  prep_kernel     <<<NB,  256, 0, stream>>>(c, pack, cnt, gmm);
  count_kernel    <<<NB,  256, 0, stream>>>(c, cnt, cellid);
  scan_kernel     <<<1,  1024, 0, stream>>>(cnt, cstart, cursor);
  scatter_kernel  <<<NB,  256, 0, stream>>>(pack, cellid, cursor, sorted, sid);
  knn_kernel      <<<(NN*4 + 255) / 256, 256, 0, stream>>>(sorted, cstart, nbr);
  edge_kernel     <<<250, 256, 0, stream>>>(c, nbr, ew, gmm);
  ewdeg_kernel    <<<NB,  256, 0, stream>>>(gmm, ew, dis);
  gemm_kernel<FIN><<<NN * HH / 256, 256, 0, stream>>>(x, W1, xw);
  agg_relu_kernel <<<NN / 4,        256, 0, stream>>>(xw, nbr, ew, dis, b1, sid, h1);
  gemm_kernel<HH> <<<NN * HH / 256, 256, 0, stream>>>(h1, W2, xw);
  agg_fc_kernel   <<<NN / 4,        256, 0, stream>>>(xw, nbr, ew, dis, b2, Wfc, bfc, sid, out);
}